// Round 11
// baseline (518.504 us; speedup 1.0000x reference)
//
#include <hip/hip_runtime.h>
#include <hip/hip_cooperative_groups.h>
#include <math.h>

namespace cg = cooperative_groups;

#define NDET 256
#define NTRK 256
#define NV   512
#define PPTS 512

typedef short bf16x8 __attribute__((ext_vector_type(8)));
typedef float f32x4  __attribute__((ext_vector_type(4)));

__device__ __forceinline__ float sigf(float x) { return 1.f / (1.f + __expf(-x)); }
__device__ __forceinline__ float ftanh(float x) {
    const float xc = fmaxf(fminf(x, 15.f), -15.f);
    const float e = __expf(2.f * xc);
    return (e - 1.f) / (e + 1.f);
}

__device__ __forceinline__ short f2bf(float f) {
    unsigned u = __float_as_uint(f);
    u += 0x7fffu + ((u >> 16) & 1u);          // RNE
    return (short)(u >> 16);
}
__device__ __forceinline__ unsigned pack2bf(float lo, float hi) {
    return (unsigned)(unsigned short)f2bf(lo) | ((unsigned)(unsigned short)f2bf(hi) << 16);
}
__device__ __forceinline__ bf16x8 load_frag_bf16(const float* __restrict__ src) {
    const float4 a = *(const float4*)src;
    const float4 b = *(const float4*)(src + 4);
    bf16x8 r;
    r[0] = f2bf(a.x); r[1] = f2bf(a.y); r[2] = f2bf(a.z); r[3] = f2bf(a.w);
    r[4] = f2bf(b.x); r[5] = f2bf(b.y); r[6] = f2bf(b.z); r[7] = f2bf(b.w);
    return r;
}

// ---------------------------------------------------------------------------
// PointNet (bf16 MFMA) + det-motion tail — unchanged from round 9/10.
// Kept separate from LSTM (merging forces one VGPR budget -> LSTM spill,
// measured regression rounds 6/7).
// ---------------------------------------------------------------------------
__global__ __launch_bounds__(256) void pointnet_kernel(
    const float* __restrict__ det_pts, const float* __restrict__ track_pts,
    const float* __restrict__ w1, const float* __restrict__ b1,
    const float* __restrict__ w2, const float* __restrict__ b2,
    const float* __restrict__ w3, const float* __restrict__ b3,
    const float* __restrict__ det_boxes,
    const float* __restrict__ dw1, const float* __restrict__ db1,
    const float* __restrict__ dw2, const float* __restrict__ db2,
    float* __restrict__ hout)
{
    __shared__ __align__(16) short sH1[64][72];
    __shared__ __align__(16) short sH2[64][136];
    __shared__ __align__(16) float sX[320];
    __shared__ float sW1f[64][6];
    __shared__ float sB1[64];
    __shared__ float sbox[9];
    __shared__ float sh32[32];

    const int t  = threadIdx.x;
    const int b  = blockIdx.x;
    const int w  = t >> 6;
    const int ln = t & 15;
    const int kq = (t >> 4) & 3;
    const float* x = (b < NDET) ? (det_pts + (size_t)b * PPTS * 5)
                                : (track_pts + (size_t)(b - NDET) * PPTS * 5);

    for (int i = t; i < 320; i += 256) sW1f[i / 5][i % 5] = w1[i];
    if (t < 64) sB1[t] = b1[t];

    bf16x8 bf2[2][2];
#pragma unroll
    for (int nt = 0; nt < 2; ++nt)
#pragma unroll
        for (int Kt = 0; Kt < 2; ++Kt)
            bf2[nt][Kt] = load_frag_bf16(w2 + (size_t)(32 * w + 16 * nt + ln) * 64 + kq * 8 + 32 * Kt);
    bf16x8 bf3[4];
#pragma unroll
    for (int Kt = 0; Kt < 4; ++Kt)
        bf3[Kt] = load_frag_bf16(w3 + (size_t)(16 * w + ln) * 128 + kq * 8 + 32 * Kt);
    float bn[2];
#pragma unroll
    for (int nt = 0; nt < 2; ++nt) bn[nt] = b2[32 * w + 16 * nt + ln];
    __syncthreads();

    float runmax[4] = {-1e30f, -1e30f, -1e30f, -1e30f};

    const int pt = t & 63;
    for (int c = 0; c < PPTS / 64; ++c) {
        for (int i = t; i < 320; i += 256) sX[i] = x[c * 320 + i];
        __syncthreads();
        {
            float xv[5];
#pragma unroll
            for (int k = 0; k < 5; ++k) xv[k] = sX[pt * 5 + k];
#pragma unroll
            for (int jj = 0; jj < 8; ++jj) {
                const int d0 = w * 16 + 2 * jj;
                float a0 = sB1[d0], a1 = sB1[d0 + 1];
#pragma unroll
                for (int k = 0; k < 5; ++k) {
                    a0 = fmaf(xv[k], sW1f[d0][k], a0);
                    a1 = fmaf(xv[k], sW1f[d0 + 1][k], a1);
                }
                *(unsigned*)&sH1[pt][d0] = pack2bf(fmaxf(a0, 0.f), fmaxf(a1, 0.f));
            }
        }
        __syncthreads();
        {
            bf16x8 af[4][2];
#pragma unroll
            for (int Mt = 0; Mt < 4; ++Mt)
#pragma unroll
                for (int Kt = 0; Kt < 2; ++Kt)
                    af[Mt][Kt] = *(const bf16x8*)&sH1[16 * Mt + ln][kq * 8 + 32 * Kt];
#pragma unroll
            for (int Mt = 0; Mt < 4; ++Mt) {
#pragma unroll
                for (int nt = 0; nt < 2; ++nt) {
                    f32x4 cacc = {0.f, 0.f, 0.f, 0.f};
                    cacc = __builtin_amdgcn_mfma_f32_16x16x32_bf16(af[Mt][0], bf2[nt][0], cacc, 0, 0, 0);
                    cacc = __builtin_amdgcn_mfma_f32_16x16x32_bf16(af[Mt][1], bf2[nt][1], cacc, 0, 0, 0);
                    const int col = 32 * w + 16 * nt + ln;
#pragma unroll
                    for (int r = 0; r < 4; ++r)
                        sH2[16 * Mt + kq * 4 + r][col] = f2bf(fmaxf(cacc[r] + bn[nt], 0.f));
                }
            }
        }
        __syncthreads();
        {
#pragma unroll
            for (int Mt = 0; Mt < 4; ++Mt) {
                f32x4 cacc = {0.f, 0.f, 0.f, 0.f};
#pragma unroll
                for (int Kt = 0; Kt < 4; ++Kt) {
                    const bf16x8 a = *(const bf16x8*)&sH2[16 * Mt + ln][kq * 8 + 32 * Kt];
                    cacc = __builtin_amdgcn_mfma_f32_16x16x32_bf16(a, bf3[Kt], cacc, 0, 0, 0);
                }
#pragma unroll
                for (int r = 0; r < 4; ++r) runmax[r] = fmaxf(runmax[r], cacc[r]);
            }
        }
        __syncthreads();
    }

    float rm = fmaxf(fmaxf(runmax[0], runmax[1]), fmaxf(runmax[2], runmax[3]));
    rm = fmaxf(rm, __shfl_xor(rm, 16));
    rm = fmaxf(rm, __shfl_xor(rm, 32));
    if ((t & 63) < 16) {
        const int n = 16 * w + ln;
        hout[b * 128 + n] = rm + b3[n];
    }

    if (b < NDET) {
        if (t < 9) sbox[t] = det_boxes[b * 9 + t];
        __syncthreads();
        if (t < 32) {
            float a = db1[t];
#pragma unroll
            for (int k = 0; k < 9; ++k) a = fmaf(dw1[t * 9 + k], sbox[k], a);
            sh32[t] = fmaxf(a, 0.f);
        }
        __syncthreads();
        if (t < 64) {
            float a = db2[t];
#pragma unroll
            for (int k = 0; k < 32; ++k) a = fmaf(dw2[t * 32 + k], sh32[k], a);
            hout[b * 128 + 64 + t] = a;
        }
    }
}

// ---------------------------------------------------------------------------
// Fused 2-layer LSTM, row-parallel (VGPR 256, no spill) — unchanged from R10.
// ---------------------------------------------------------------------------
__global__ __launch_bounds__(256, 1) void lstm_kernel(
    const float* __restrict__ track_boxes,
    const float* __restrict__ wih0, const float* __restrict__ whh0,
    const float* __restrict__ bih0, const float* __restrict__ bhh0,
    const float* __restrict__ wih1, const float* __restrict__ whh1,
    const float* __restrict__ bih1, const float* __restrict__ bhh1,
    float* __restrict__ hout)
{
    __shared__ float sx[90];
    __shared__ float sg[256];
    __shared__ __align__(16) float sh0[64];
    __shared__ __align__(16) float sh1[64];

    const int t = threadIdx.x;
    const int m = blockIdx.x;
    const int u = t & 63;

    if (t < 90) sx[t] = track_boxes[m * 90 + t];
    if (t < 64) { sh0[t] = 0.f; sh1[t] = 0.f; }

    float w0[9];
#pragma unroll
    for (int k = 0; k < 9; ++k) w0[k] = wih0[t * 9 + k];
    float4 wr0[16], wi1[16], wr1[16];
    {
        const float4* p0 = (const float4*)(whh0 + t * 64);
        const float4* p1 = (const float4*)(wih1 + t * 64);
        const float4* p2 = (const float4*)(whh1 + t * 64);
#pragma unroll
        for (int k = 0; k < 16; ++k) { wr0[k] = p0[k]; wi1[k] = p1[k]; wr1[k] = p2[k]; }
    }
    const float bias0 = bih0[t] + bhh0[t];
    const float bias1 = bih1[t] + bhh1[t];

    float c0 = 0.f, c1 = 0.f, h1reg = 0.f;
    __syncthreads();

    for (int s = 0; s < 10; ++s) {
        {
            float acc0 = bias0, acc1 = 0.f, acc2 = 0.f, acc3 = 0.f;
#pragma unroll
            for (int k = 0; k < 9; ++k) acc0 = fmaf(w0[k], sx[s * 9 + k], acc0);
            const float4* hv = (const float4*)sh0;
#pragma unroll
            for (int k = 0; k < 16; k += 4) {
                float4 hA = hv[k], hB = hv[k + 1], hC = hv[k + 2], hD = hv[k + 3];
                acc0 = fmaf(wr0[k].x, hA.x, acc0); acc0 = fmaf(wr0[k].y, hA.y, acc0);
                acc0 = fmaf(wr0[k].z, hA.z, acc0); acc0 = fmaf(wr0[k].w, hA.w, acc0);
                acc1 = fmaf(wr0[k+1].x, hB.x, acc1); acc1 = fmaf(wr0[k+1].y, hB.y, acc1);
                acc1 = fmaf(wr0[k+1].z, hB.z, acc1); acc1 = fmaf(wr0[k+1].w, hB.w, acc1);
                acc2 = fmaf(wr0[k+2].x, hC.x, acc2); acc2 = fmaf(wr0[k+2].y, hC.y, acc2);
                acc2 = fmaf(wr0[k+2].z, hC.z, acc2); acc2 = fmaf(wr0[k+2].w, hC.w, acc2);
                acc3 = fmaf(wr0[k+3].x, hD.x, acc3); acc3 = fmaf(wr0[k+3].y, hD.y, acc3);
                acc3 = fmaf(wr0[k+3].z, hD.z, acc3); acc3 = fmaf(wr0[k+3].w, hD.w, acc3);
            }
            sg[t] = (acc0 + acc1) + (acc2 + acc3);
        }
        __syncthreads();
        if (t < 64) {
            const float gi = sg[u], gf = sg[64 + u], gg = sg[128 + u], go = sg[192 + u];
            c0 = sigf(gf) * c0 + sigf(gi) * ftanh(gg);
            sh0[u] = sigf(go) * ftanh(c0);
        }
        __syncthreads();
        {
            float acc0 = bias1, acc1 = 0.f, acc2 = 0.f, acc3 = 0.f;
            const float4* xv = (const float4*)sh0;
            const float4* hv = (const float4*)sh1;
#pragma unroll
            for (int k = 0; k < 16; k += 4) {
                float4 xA = xv[k], xB = xv[k + 1], xC = xv[k + 2], xD = xv[k + 3];
                acc0 = fmaf(wi1[k].x, xA.x, acc0); acc0 = fmaf(wi1[k].y, xA.y, acc0);
                acc0 = fmaf(wi1[k].z, xA.z, acc0); acc0 = fmaf(wi1[k].w, xA.w, acc0);
                acc1 = fmaf(wi1[k+1].x, xB.x, acc1); acc1 = fmaf(wi1[k+1].y, xB.y, acc1);
                acc1 = fmaf(wi1[k+1].z, xB.z, acc1); acc1 = fmaf(wi1[k+1].w, xB.w, acc1);
                acc2 = fmaf(wi1[k+2].x, xC.x, acc2); acc2 = fmaf(wi1[k+2].y, xC.y, acc2);
                acc2 = fmaf(wi1[k+2].z, xC.z, acc2); acc2 = fmaf(wi1[k+2].w, xC.w, acc2);
                acc3 = fmaf(wi1[k+3].x, xD.x, acc3); acc3 = fmaf(wi1[k+3].y, xD.y, acc3);
                acc3 = fmaf(wi1[k+3].z, xD.z, acc3); acc3 = fmaf(wi1[k+3].w, xD.w, acc3);
            }
#pragma unroll
            for (int k = 0; k < 16; k += 4) {
                float4 hA = hv[k], hB = hv[k + 1], hC = hv[k + 2], hD = hv[k + 3];
                acc0 = fmaf(wr1[k].x, hA.x, acc0); acc0 = fmaf(wr1[k].y, hA.y, acc0);
                acc0 = fmaf(wr1[k].z, hA.z, acc0); acc0 = fmaf(wr1[k].w, hA.w, acc0);
                acc1 = fmaf(wr1[k+1].x, hB.x, acc1); acc1 = fmaf(wr1[k+1].y, hB.y, acc1);
                acc1 = fmaf(wr1[k+1].z, hB.z, acc1); acc1 = fmaf(wr1[k+1].w, hB.w, acc1);
                acc2 = fmaf(wr1[k+2].x, hC.x, acc2); acc2 = fmaf(wr1[k+2].y, hC.y, acc2);
                acc2 = fmaf(wr1[k+2].z, hC.z, acc2); acc2 = fmaf(wr1[k+2].w, hC.w, acc2);
                acc3 = fmaf(wr1[k+3].x, hD.x, acc3); acc3 = fmaf(wr1[k+3].y, hD.y, acc3);
                acc3 = fmaf(wr1[k+3].z, hD.z, acc3); acc3 = fmaf(wr1[k+3].w, hD.w, acc3);
            }
            sg[t] = (acc0 + acc1) + (acc2 + acc3);
        }
        __syncthreads();
        if (t < 64) {
            const float gi = sg[u], gf = sg[64 + u], gg = sg[128 + u], go = sg[192 + u];
            c1 = sigf(gf) * c1 + sigf(gi) * ftanh(gg);
            h1reg = sigf(go) * ftanh(c1);
            sh1[u] = h1reg;
        }
        __syncthreads();
    }

    if (t < 64) hout[(size_t)(NDET + m) * 128 + 64 + u] = h1reg;
}

// ---------------------------------------------------------------------------
// Cooperative backend: layer-0 GEMM + 4x(neighbor-max + combine + next GEMM)
// + both uprojs + both affinity outputs, one dispatch with grid.sync().
// Mask built ONCE (adjacency is layer-invariant). Own Th/Ph row carried in
// registers across layers. All arithmetic orders identical to the split
// kernels -> bit-identical output.
// ---------------------------------------------------------------------------
__global__ void backend_kernel(
    const float* __restrict__ hA, const int* __restrict__ adj,
    const float* __restrict__ gc_wt, const float* __restrict__ gc_bt,
    const float* __restrict__ gc_wp, const float* __restrict__ gc_bp,
    const float* __restrict__ er_w1, const float* __restrict__ er_b1,
    const float* __restrict__ er_w2, const float* __restrict__ er_b2,
    float* __restrict__ ThA, float* __restrict__ PhA,
    float* __restrict__ ThB, float* __restrict__ PhB,
    float* __restrict__ uu1, float* __restrict__ uu2,
    float* __restrict__ out)
{
    cg::grid_group grid = cg::this_grid();

    __shared__ __align__(16) float srow[128];
    __shared__ float sneg[NV];
    __shared__ __align__(16) float4 sred[4][32];
    __shared__ __align__(16) float sh[128];
    __shared__ float sui[64], sw2v[64], sb1v[64];

    const int t = threadIdx.x, i = blockIdx.x;
    const int l32 = t & 31, grp = t >> 5;
    const size_t WSZ = 128 * 128;

    // ---- mask once (layer-invariant)
    for (int j = t; j < NV; j += 128)
        sneg[j] = ((adj[j * NV + i] != 0) || (j == i)) ? 0.f : -3e38f;

    // ---- phase A: layer-0 GEMM for own row
    srow[t] = hA[(size_t)i * 128 + t];
    __syncthreads();
    float thi, phi;
    {
        const float4* hr = (const float4*)srow;
        const float4* wtr = (const float4*)(gc_wt + (size_t)t * 128);
        const float4* wpr = (const float4*)(gc_wp + (size_t)t * 128);
        float aT = 0.f, aP = gc_bp[t];
#pragma unroll 8
        for (int k = 0; k < 32; ++k) {
            const float4 h = hr[k];
            const float4 a = wtr[k];
            aT = fmaf(a.x, h.x, aT); aT = fmaf(a.y, h.y, aT);
            aT = fmaf(a.z, h.z, aT); aT = fmaf(a.w, h.w, aT);
            const float4 b = wpr[k];
            aP = fmaf(b.x, h.x, aP); aP = fmaf(b.y, h.y, aP);
            aP = fmaf(b.z, h.z, aP); aP = fmaf(b.w, h.w, aP);
        }
        ThA[(size_t)i * 128 + t] = aT;
        PhA[(size_t)i * 128 + t] = aP;
        thi = aT; phi = aP;
    }
    grid.sync();

    float* Tin = ThA; float* Tout = ThB;
    float* Pout = PhB;
    for (int k = 0; k < 4; ++k) {
        const bool active = (k < 3) || (i < NDET);
        if (active) {
            const float btv = gc_bt[k * 128 + t];
            float4 mx = {-3e38f, -3e38f, -3e38f, -3e38f};
            const float* __restrict__ thp = Tin + 4 * l32;
#pragma unroll 4
            for (int jb = 0; jb < NV; jb += 16) {
                float4 v[4];
#pragma unroll
                for (int jj = 0; jj < 4; ++jj)
                    v[jj] = *(const float4*)&thp[(size_t)(jb + 4 * jj + grp) * 128];
#pragma unroll
                for (int jj = 0; jj < 4; ++jj) {
                    const float s = sneg[jb + 4 * jj + grp];
                    mx.x = fmaxf(mx.x, v[jj].x + s);
                    mx.y = fmaxf(mx.y, v[jj].y + s);
                    mx.z = fmaxf(mx.z, v[jj].z + s);
                    mx.w = fmaxf(mx.w, v[jj].w + s);
                }
            }
            sred[grp][l32] = mx;
            __syncthreads();

            const float* rf = (const float*)sred;
            const float m = fmaxf(fmaxf(rf[t], rf[128 + t]), fmaxf(rf[256 + t], rf[384 + t]));
            sh[t] = fmaxf(m - thi + btv + phi, 0.f);
            __syncthreads();

            const float4* hr = (const float4*)sh;
            if (k < 3) {
                const float* wtn = gc_wt + (size_t)(k + 1) * WSZ;
                const float* wpn = gc_wp + (size_t)(k + 1) * WSZ;
                const float4* wtr = (const float4*)(wtn + (size_t)t * 128);
                const float4* wpr = (const float4*)(wpn + (size_t)t * 128);
                float aT = 0.f, aP = gc_bp[(k + 1) * 128 + t];
#pragma unroll 8
                for (int kk = 0; kk < 32; ++kk) {
                    const float4 h = hr[kk];
                    const float4 a = wtr[kk];
                    aT = fmaf(a.x, h.x, aT); aT = fmaf(a.y, h.y, aT);
                    aT = fmaf(a.z, h.z, aT); aT = fmaf(a.w, h.w, aT);
                    const float4 b = wpr[kk];
                    aP = fmaf(b.x, h.x, aP); aP = fmaf(b.y, h.y, aP);
                    aP = fmaf(b.z, h.z, aP); aP = fmaf(b.w, h.w, aP);
                }
                Tout[(size_t)i * 128 + t] = aT;
                Pout[(size_t)i * 128 + t] = aP;
                thi = aT; phi = aP;
            }
            if ((k == 0 || k == 3) && i < NDET && t < 64) {
                float* uu = (k == 0) ? uu1 : uu2;
                const float4* wr = (const float4*)(er_w1 + (size_t)t * 128);
                float a = 0.f;
#pragma unroll 8
                for (int kk = 0; kk < 32; ++kk) {
                    const float4 h = hr[kk], wv = wr[kk];
                    a = fmaf(wv.x, h.x, a); a = fmaf(wv.y, h.y, a);
                    a = fmaf(wv.z, h.z, a); a = fmaf(wv.w, h.w, a);
                }
                uu[(size_t)i * 64 + t] = a;
            }
        }
        // ping-pong
        float* tmp = Tin; Tin = Tout; Tout = tmp;
        Pout = (Pout == PhB) ? PhA : PhB;
        grid.sync();
    }

    // ---- phase C: both affinity maps. block i<256 -> aff1 row i from uu1;
    // block i>=256 -> aff_final row i-256 from uu2.
    const int row = i & (NDET - 1);
    const float* u = (i < NDET) ? uu1 : uu2;
    float* o = (i < NDET) ? out : out + NDET * NTRK;
    if (t < 64) { sui[t] = u[row * 64 + t]; sw2v[t] = er_w2[t]; sb1v[t] = er_b1[t]; }
    __syncthreads();
#pragma unroll
    for (int jj = 0; jj < 2; ++jj) {
        const int j = t + 128 * jj;
        const float4* ur = (const float4*)(u + (size_t)j * 64);
        float a = er_b2[0];
#pragma unroll
        for (int k = 0; k < 16; ++k) {
            const float4 uv = ur[k];
            const int k4 = k * 4;
            a = fmaf(sw2v[k4 + 0], fmaxf(uv.x - sui[k4 + 0] + sb1v[k4 + 0], 0.f), a);
            a = fmaf(sw2v[k4 + 1], fmaxf(uv.y - sui[k4 + 1] + sb1v[k4 + 1], 0.f), a);
            a = fmaf(sw2v[k4 + 2], fmaxf(uv.z - sui[k4 + 2] + sb1v[k4 + 2], 0.f), a);
            a = fmaf(sw2v[k4 + 3], fmaxf(uv.w - sui[k4 + 3] + sb1v[k4 + 3], 0.f), a);
        }
        o[row * 256 + j] = 1.f / (1.f + __expf(-a));
    }
}

// ---------------------------------------------------------------------------
extern "C" void kernel_launch(void* const* d_in, const int* in_sizes, int n_in,
                              void* d_out, int out_size, void* d_ws, size_t ws_size,
                              hipStream_t stream)
{
    const float* det_pts     = (const float*)d_in[0];
    const float* det_boxes   = (const float*)d_in[1];
    const float* track_pts   = (const float*)d_in[2];
    const float* track_boxes = (const float*)d_in[3];
    const int*   adj         = (const int*)d_in[4];
    const float* pn_w1 = (const float*)d_in[5],  *pn_b1 = (const float*)d_in[6];
    const float* pn_w2 = (const float*)d_in[7],  *pn_b2 = (const float*)d_in[8];
    const float* pn_w3 = (const float*)d_in[9],  *pn_b3 = (const float*)d_in[10];
    const float* dm_w1 = (const float*)d_in[11], *dm_b1 = (const float*)d_in[12];
    const float* dm_w2 = (const float*)d_in[13], *dm_b2 = (const float*)d_in[14];
    const float* l0_wih = (const float*)d_in[15], *l0_whh = (const float*)d_in[16];
    const float* l0_bih = (const float*)d_in[17], *l0_bhh = (const float*)d_in[18];
    const float* l1_wih = (const float*)d_in[19], *l1_whh = (const float*)d_in[20];
    const float* l1_bih = (const float*)d_in[21], *l1_bhh = (const float*)d_in[22];
    const float* gc_wt = (const float*)d_in[23], *gc_bt = (const float*)d_in[24];
    const float* gc_wp = (const float*)d_in[25], *gc_bp = (const float*)d_in[26];
    const float* er_w1 = (const float*)d_in[27], *er_b1 = (const float*)d_in[28];
    const float* er_w2 = (const float*)d_in[29], *er_b2 = (const float*)d_in[30];
    float* out = (float*)d_out;

    float* hA  = (float*)d_ws;           // [512][128]
    float* Th  = hA  + NV * 128;         // [512][128]
    float* Ph  = Th  + NV * 128;         // [512][128]
    float* Th2 = Ph  + NV * 128;         // [512][128]
    float* Ph2 = Th2 + NV * 128;         // [512][128]
    float* uu1 = Ph2 + NV * 128;         // [256][64]
    float* uu2 = uu1 + NDET * 64;        // [256][64]

    pointnet_kernel<<<NV, 256, 0, stream>>>(det_pts, track_pts,
        pn_w1, pn_b1, pn_w2, pn_b2, pn_w3, pn_b3,
        det_boxes, dm_w1, dm_b1, dm_w2, dm_b2, hA);
    lstm_kernel<<<NTRK, 256, 0, stream>>>(track_boxes,
        l0_wih, l0_whh, l0_bih, l0_bhh, l1_wih, l1_whh, l1_bih, l1_bhh, hA);

    void* args[] = {
        (void*)&hA, (void*)&adj,
        (void*)&gc_wt, (void*)&gc_bt, (void*)&gc_wp, (void*)&gc_bp,
        (void*)&er_w1, (void*)&er_b1, (void*)&er_w2, (void*)&er_b2,
        (void*)&Th, (void*)&Ph, (void*)&Th2, (void*)&Ph2,
        (void*)&uu1, (void*)&uu2, (void*)&out
    };
    hipLaunchCooperativeKernel((const void*)backend_kernel,
                               dim3(NV), dim3(128), args, 0, stream);
}

// Round 12
// 243.848 us; speedup vs baseline: 2.1263x; 2.1263x over previous
//
#include <hip/hip_runtime.h>
#include <math.h>

#define NDET 256
#define NTRK 256
#define NV   512
#define PPTS 512

typedef short bf16x8 __attribute__((ext_vector_type(8)));
typedef float f32x4  __attribute__((ext_vector_type(4)));

__device__ __forceinline__ float sigf(float x) { return 1.f / (1.f + __expf(-x)); }
__device__ __forceinline__ float ftanh(float x) {
    const float xc = fmaxf(fminf(x, 15.f), -15.f);   // avoid inf/inf
    const float e = __expf(2.f * xc);
    return (e - 1.f) / (e + 1.f);
}

__device__ __forceinline__ short f2bf(float f) {
    unsigned u = __float_as_uint(f);
    u += 0x7fffu + ((u >> 16) & 1u);          // RNE
    return (short)(u >> 16);
}
__device__ __forceinline__ unsigned pack2bf(float lo, float hi) {
    return (unsigned)(unsigned short)f2bf(lo) | ((unsigned)(unsigned short)f2bf(hi) << 16);
}
__device__ __forceinline__ bf16x8 load_frag_bf16(const float* __restrict__ src) {
    const float4 a = *(const float4*)src;
    const float4 b = *(const float4*)(src + 4);
    bf16x8 r;
    r[0] = f2bf(a.x); r[1] = f2bf(a.y); r[2] = f2bf(a.z); r[3] = f2bf(a.w);
    r[4] = f2bf(b.x); r[5] = f2bf(b.y); r[6] = f2bf(b.z); r[7] = f2bf(b.w);
    return r;
}

// ---------------------------------------------------------------------------
// PointNet (bf16 MFMA stages 2/3) + fused det-motion MLP tail for det blocks.
// W2/W3 fragments loaded directly from global into registers (L2-resident).
// Kept separate from LSTM (merge -> single VGPR budget -> LSTM spill; R6/7).
// Cooperative grid.sync measured catastrophically slow on gfx950 (R11):
// keep the launch-per-stage structure.
// ---------------------------------------------------------------------------
__global__ __launch_bounds__(256) void pointnet_kernel(
    const float* __restrict__ det_pts, const float* __restrict__ track_pts,
    const float* __restrict__ w1, const float* __restrict__ b1,
    const float* __restrict__ w2, const float* __restrict__ b2,
    const float* __restrict__ w3, const float* __restrict__ b3,
    const float* __restrict__ det_boxes,
    const float* __restrict__ dw1, const float* __restrict__ db1,
    const float* __restrict__ dw2, const float* __restrict__ db2,
    float* __restrict__ hout)
{
    __shared__ __align__(16) short sH1[64][72];
    __shared__ __align__(16) short sH2[64][136];
    __shared__ __align__(16) float sX[320];
    __shared__ float sW1f[64][6];
    __shared__ float sB1[64];
    __shared__ float sbox[9];
    __shared__ float sh32[32];

    const int t  = threadIdx.x;
    const int b  = blockIdx.x;
    const int w  = t >> 6;
    const int ln = t & 15;
    const int kq = (t >> 4) & 3;
    const float* x = (b < NDET) ? (det_pts + (size_t)b * PPTS * 5)
                                : (track_pts + (size_t)(b - NDET) * PPTS * 5);

    for (int i = t; i < 320; i += 256) sW1f[i / 5][i % 5] = w1[i];
    if (t < 64) sB1[t] = b1[t];

    bf16x8 bf2[2][2];
#pragma unroll
    for (int nt = 0; nt < 2; ++nt)
#pragma unroll
        for (int Kt = 0; Kt < 2; ++Kt)
            bf2[nt][Kt] = load_frag_bf16(w2 + (size_t)(32 * w + 16 * nt + ln) * 64 + kq * 8 + 32 * Kt);
    bf16x8 bf3[4];
#pragma unroll
    for (int Kt = 0; Kt < 4; ++Kt)
        bf3[Kt] = load_frag_bf16(w3 + (size_t)(16 * w + ln) * 128 + kq * 8 + 32 * Kt);
    float bn[2];
#pragma unroll
    for (int nt = 0; nt < 2; ++nt) bn[nt] = b2[32 * w + 16 * nt + ln];
    __syncthreads();

    float runmax[4] = {-1e30f, -1e30f, -1e30f, -1e30f};

    const int pt = t & 63;
    for (int c = 0; c < PPTS / 64; ++c) {
        for (int i = t; i < 320; i += 256) sX[i] = x[c * 320 + i];
        __syncthreads();
        {
            float xv[5];
#pragma unroll
            for (int k = 0; k < 5; ++k) xv[k] = sX[pt * 5 + k];
#pragma unroll
            for (int jj = 0; jj < 8; ++jj) {
                const int d0 = w * 16 + 2 * jj;
                float a0 = sB1[d0], a1 = sB1[d0 + 1];
#pragma unroll
                for (int k = 0; k < 5; ++k) {
                    a0 = fmaf(xv[k], sW1f[d0][k], a0);
                    a1 = fmaf(xv[k], sW1f[d0 + 1][k], a1);
                }
                *(unsigned*)&sH1[pt][d0] = pack2bf(fmaxf(a0, 0.f), fmaxf(a1, 0.f));
            }
        }
        __syncthreads();
        {
            bf16x8 af[4][2];
#pragma unroll
            for (int Mt = 0; Mt < 4; ++Mt)
#pragma unroll
                for (int Kt = 0; Kt < 2; ++Kt)
                    af[Mt][Kt] = *(const bf16x8*)&sH1[16 * Mt + ln][kq * 8 + 32 * Kt];
#pragma unroll
            for (int Mt = 0; Mt < 4; ++Mt) {
#pragma unroll
                for (int nt = 0; nt < 2; ++nt) {
                    f32x4 cacc = {0.f, 0.f, 0.f, 0.f};
                    cacc = __builtin_amdgcn_mfma_f32_16x16x32_bf16(af[Mt][0], bf2[nt][0], cacc, 0, 0, 0);
                    cacc = __builtin_amdgcn_mfma_f32_16x16x32_bf16(af[Mt][1], bf2[nt][1], cacc, 0, 0, 0);
                    const int col = 32 * w + 16 * nt + ln;
#pragma unroll
                    for (int r = 0; r < 4; ++r)
                        sH2[16 * Mt + kq * 4 + r][col] = f2bf(fmaxf(cacc[r] + bn[nt], 0.f));
                }
            }
        }
        __syncthreads();
        {
#pragma unroll
            for (int Mt = 0; Mt < 4; ++Mt) {
                f32x4 cacc = {0.f, 0.f, 0.f, 0.f};
#pragma unroll
                for (int Kt = 0; Kt < 4; ++Kt) {
                    const bf16x8 a = *(const bf16x8*)&sH2[16 * Mt + ln][kq * 8 + 32 * Kt];
                    cacc = __builtin_amdgcn_mfma_f32_16x16x32_bf16(a, bf3[Kt], cacc, 0, 0, 0);
                }
#pragma unroll
                for (int r = 0; r < 4; ++r) runmax[r] = fmaxf(runmax[r], cacc[r]);
            }
        }
        __syncthreads();
    }

    float rm = fmaxf(fmaxf(runmax[0], runmax[1]), fmaxf(runmax[2], runmax[3]));
    rm = fmaxf(rm, __shfl_xor(rm, 16));
    rm = fmaxf(rm, __shfl_xor(rm, 32));
    if ((t & 63) < 16) {
        const int n = 16 * w + ln;
        hout[b * 128 + n] = rm + b3[n];
    }

    if (b < NDET) {
        if (t < 9) sbox[t] = det_boxes[b * 9 + t];
        __syncthreads();
        if (t < 32) {
            float a = db1[t];
#pragma unroll
            for (int k = 0; k < 9; ++k) a = fmaf(dw1[t * 9 + k], sbox[k], a);
            sh32[t] = fmaxf(a, 0.f);
        }
        __syncthreads();
        if (t < 64) {
            float a = db2[t];
#pragma unroll
            for (int k = 0; k < 32; ++k) a = fmaf(dw2[t * 32 + k], sh32[k], a);
            hout[b * 128 + 64 + t] = a;
        }
    }
}

// ---------------------------------------------------------------------------
// Fused 2-layer LSTM, row-parallel (VGPR 256, no spill). Fast transcendentals.
// ---------------------------------------------------------------------------
__global__ __launch_bounds__(256, 1) void lstm_kernel(
    const float* __restrict__ track_boxes,
    const float* __restrict__ wih0, const float* __restrict__ whh0,
    const float* __restrict__ bih0, const float* __restrict__ bhh0,
    const float* __restrict__ wih1, const float* __restrict__ whh1,
    const float* __restrict__ bih1, const float* __restrict__ bhh1,
    float* __restrict__ hout)
{
    __shared__ float sx[90];
    __shared__ float sg[256];
    __shared__ __align__(16) float sh0[64];
    __shared__ __align__(16) float sh1[64];

    const int t = threadIdx.x;
    const int m = blockIdx.x;
    const int u = t & 63;

    if (t < 90) sx[t] = track_boxes[m * 90 + t];
    if (t < 64) { sh0[t] = 0.f; sh1[t] = 0.f; }

    float w0[9];
#pragma unroll
    for (int k = 0; k < 9; ++k) w0[k] = wih0[t * 9 + k];
    float4 wr0[16], wi1[16], wr1[16];
    {
        const float4* p0 = (const float4*)(whh0 + t * 64);
        const float4* p1 = (const float4*)(wih1 + t * 64);
        const float4* p2 = (const float4*)(whh1 + t * 64);
#pragma unroll
        for (int k = 0; k < 16; ++k) { wr0[k] = p0[k]; wi1[k] = p1[k]; wr1[k] = p2[k]; }
    }
    const float bias0 = bih0[t] + bhh0[t];
    const float bias1 = bih1[t] + bhh1[t];

    float c0 = 0.f, c1 = 0.f, h1reg = 0.f;
    __syncthreads();

    for (int s = 0; s < 10; ++s) {
        {
            float acc0 = bias0, acc1 = 0.f, acc2 = 0.f, acc3 = 0.f;
#pragma unroll
            for (int k = 0; k < 9; ++k) acc0 = fmaf(w0[k], sx[s * 9 + k], acc0);
            const float4* hv = (const float4*)sh0;
#pragma unroll
            for (int k = 0; k < 16; k += 4) {
                float4 hA = hv[k], hB = hv[k + 1], hC = hv[k + 2], hD = hv[k + 3];
                acc0 = fmaf(wr0[k].x, hA.x, acc0); acc0 = fmaf(wr0[k].y, hA.y, acc0);
                acc0 = fmaf(wr0[k].z, hA.z, acc0); acc0 = fmaf(wr0[k].w, hA.w, acc0);
                acc1 = fmaf(wr0[k+1].x, hB.x, acc1); acc1 = fmaf(wr0[k+1].y, hB.y, acc1);
                acc1 = fmaf(wr0[k+1].z, hB.z, acc1); acc1 = fmaf(wr0[k+1].w, hB.w, acc1);
                acc2 = fmaf(wr0[k+2].x, hC.x, acc2); acc2 = fmaf(wr0[k+2].y, hC.y, acc2);
                acc2 = fmaf(wr0[k+2].z, hC.z, acc2); acc2 = fmaf(wr0[k+2].w, hC.w, acc2);
                acc3 = fmaf(wr0[k+3].x, hD.x, acc3); acc3 = fmaf(wr0[k+3].y, hD.y, acc3);
                acc3 = fmaf(wr0[k+3].z, hD.z, acc3); acc3 = fmaf(wr0[k+3].w, hD.w, acc3);
            }
            sg[t] = (acc0 + acc1) + (acc2 + acc3);
        }
        __syncthreads();
        if (t < 64) {
            const float gi = sg[u], gf = sg[64 + u], gg = sg[128 + u], go = sg[192 + u];
            c0 = sigf(gf) * c0 + sigf(gi) * ftanh(gg);
            sh0[u] = sigf(go) * ftanh(c0);
        }
        __syncthreads();
        {
            float acc0 = bias1, acc1 = 0.f, acc2 = 0.f, acc3 = 0.f;
            const float4* xv = (const float4*)sh0;
            const float4* hv = (const float4*)sh1;
#pragma unroll
            for (int k = 0; k < 16; k += 4) {
                float4 xA = xv[k], xB = xv[k + 1], xC = xv[k + 2], xD = xv[k + 3];
                acc0 = fmaf(wi1[k].x, xA.x, acc0); acc0 = fmaf(wi1[k].y, xA.y, acc0);
                acc0 = fmaf(wi1[k].z, xA.z, acc0); acc0 = fmaf(wi1[k].w, xA.w, acc0);
                acc1 = fmaf(wi1[k+1].x, xB.x, acc1); acc1 = fmaf(wi1[k+1].y, xB.y, acc1);
                acc1 = fmaf(wi1[k+1].z, xB.z, acc1); acc1 = fmaf(wi1[k+1].w, xB.w, acc1);
                acc2 = fmaf(wi1[k+2].x, xC.x, acc2); acc2 = fmaf(wi1[k+2].y, xC.y, acc2);
                acc2 = fmaf(wi1[k+2].z, xC.z, acc2); acc2 = fmaf(wi1[k+2].w, xC.w, acc2);
                acc3 = fmaf(wi1[k+3].x, xD.x, acc3); acc3 = fmaf(wi1[k+3].y, xD.y, acc3);
                acc3 = fmaf(wi1[k+3].z, xD.z, acc3); acc3 = fmaf(wi1[k+3].w, xD.w, acc3);
            }
#pragma unroll
            for (int k = 0; k < 16; k += 4) {
                float4 hA = hv[k], hB = hv[k + 1], hC = hv[k + 2], hD = hv[k + 3];
                acc0 = fmaf(wr1[k].x, hA.x, acc0); acc0 = fmaf(wr1[k].y, hA.y, acc0);
                acc0 = fmaf(wr1[k].z, hA.z, acc0); acc0 = fmaf(wr1[k].w, hA.w, acc0);
                acc1 = fmaf(wr1[k+1].x, hB.x, acc1); acc1 = fmaf(wr1[k+1].y, hB.y, acc1);
                acc1 = fmaf(wr1[k+1].z, hB.z, acc1); acc1 = fmaf(wr1[k+1].w, hB.w, acc1);
                acc2 = fmaf(wr1[k+2].x, hC.x, acc2); acc2 = fmaf(wr1[k+2].y, hC.y, acc2);
                acc2 = fmaf(wr1[k+2].z, hC.z, acc2); acc2 = fmaf(wr1[k+2].w, hC.w, acc2);
                acc3 = fmaf(wr1[k+3].x, hD.x, acc3); acc3 = fmaf(wr1[k+3].y, hD.y, acc3);
                acc3 = fmaf(wr1[k+3].z, hD.z, acc3); acc3 = fmaf(wr1[k+3].w, hD.w, acc3);
            }
            sg[t] = (acc0 + acc1) + (acc2 + acc3);
        }
        __syncthreads();
        if (t < 64) {
            const float gi = sg[u], gf = sg[64 + u], gg = sg[128 + u], go = sg[192 + u];
            c1 = sigf(gf) * c1 + sigf(gi) * ftanh(gg);
            h1reg = sigf(go) * ftanh(c1);
            sh1[u] = h1reg;
        }
        __syncthreads();
    }

    if (t < 64) hout[(size_t)(NDET + m) * 128 + 64 + u] = h1reg;
}

// ---------------------------------------------------------------------------
// EdgeConv layer-0 GEMMs: one block per vertex.
// ---------------------------------------------------------------------------
__global__ __launch_bounds__(128) void econv_gemm_kernel(
    const float* __restrict__ hin, const float* __restrict__ wt,
    const float* __restrict__ wp, const float* __restrict__ bp,
    float* __restrict__ Th, float* __restrict__ Ph)
{
    __shared__ __align__(16) float srow[128];
    const int t = threadIdx.x, v = blockIdx.x;
    srow[t] = hin[v * 128 + t];
    __syncthreads();
    const float4* hr = (const float4*)srow;
    const float4* wtr = (const float4*)(wt + t * 128);
    const float4* wpr = (const float4*)(wp + t * 128);
    float aT = 0.f, aP = bp[t];
#pragma unroll 8
    for (int k = 0; k < 32; ++k) {
        const float4 h = hr[k];
        const float4 a = wtr[k];
        aT = fmaf(a.x, h.x, aT); aT = fmaf(a.y, h.y, aT);
        aT = fmaf(a.z, h.z, aT); aT = fmaf(a.w, h.w, aT);
        const float4 b = wpr[k];
        aP = fmaf(b.x, h.x, aP); aP = fmaf(b.y, h.y, aP);
        aP = fmaf(b.z, h.z, aP); aP = fmaf(b.w, h.w, aP);
    }
    Th[v * 128 + t] = aT;
    Ph[v * 128 + t] = aP;
}

// ---------------------------------------------------------------------------
// Fused EdgeConv: masked neighbor-max + combine + relu (h_i stays in LDS),
// then optional next-layer GEMM and optional uproj.
// ---------------------------------------------------------------------------
__global__ __launch_bounds__(128) void econv_fused_kernel(
    const int* __restrict__ adj, const float* __restrict__ Th,
    const float* __restrict__ Ph, const float* __restrict__ bt,
    const float* __restrict__ wtn, const float* __restrict__ wpn,
    const float* __restrict__ bpn,
    const float* __restrict__ erw1, float* __restrict__ uu,
    float* __restrict__ Thn, float* __restrict__ Phn)
{
    __shared__ float sneg[NV];                       // 0 / -3e38 mask bias
    __shared__ __align__(16) float4 sred[4][32];     // per-group partial max
    __shared__ __align__(16) float sh[128];          // h_i row

    const int t = threadIdx.x, i = blockIdx.x;
    const int l32 = t & 31, grp = t >> 5;

    for (int j = t; j < NV; j += 128)
        sneg[j] = ((adj[j * NV + i] != 0) || (j == i)) ? 0.f : -3e38f;

    const float thi = Th[i * 128 + t];
    const float phi = Ph[i * 128 + t];
    const float btv = bt[t];
    __syncthreads();

    float4 mx = {-3e38f, -3e38f, -3e38f, -3e38f};
    const float* __restrict__ thp = Th + 4 * l32;
#pragma unroll 4
    for (int jb = 0; jb < NV; jb += 16) {
        float4 v[4];
#pragma unroll
        for (int jj = 0; jj < 4; ++jj)
            v[jj] = *(const float4*)&thp[(size_t)(jb + 4 * jj + grp) * 128];
#pragma unroll
        for (int jj = 0; jj < 4; ++jj) {
            const float s = sneg[jb + 4 * jj + grp];
            mx.x = fmaxf(mx.x, v[jj].x + s);
            mx.y = fmaxf(mx.y, v[jj].y + s);
            mx.z = fmaxf(mx.z, v[jj].z + s);
            mx.w = fmaxf(mx.w, v[jj].w + s);
        }
    }
    sred[grp][l32] = mx;
    __syncthreads();

    const float* rf = (const float*)sred;
    const float m = fmaxf(fmaxf(rf[t], rf[128 + t]), fmaxf(rf[256 + t], rf[384 + t]));
    sh[t] = fmaxf(m - thi + btv + phi, 0.f);
    __syncthreads();

    const float4* hr = (const float4*)sh;
    if (wtn) {
        const float4* wtr = (const float4*)(wtn + t * 128);
        const float4* wpr = (const float4*)(wpn + t * 128);
        float aT = 0.f, aP = bpn[t];
#pragma unroll 8
        for (int k = 0; k < 32; ++k) {
            const float4 h = hr[k];
            const float4 a = wtr[k];
            aT = fmaf(a.x, h.x, aT); aT = fmaf(a.y, h.y, aT);
            aT = fmaf(a.z, h.z, aT); aT = fmaf(a.w, h.w, aT);
            const float4 b = wpr[k];
            aP = fmaf(b.x, h.x, aP); aP = fmaf(b.y, h.y, aP);
            aP = fmaf(b.z, h.z, aP); aP = fmaf(b.w, h.w, aP);
        }
        Thn[i * 128 + t] = aT;
        Phn[i * 128 + t] = aP;
    }
    if (erw1 && i < NDET && t < 64) {
        const float4* wr = (const float4*)(erw1 + t * 128);
        float a = 0.f;
#pragma unroll 8
        for (int k = 0; k < 32; ++k) {
            const float4 h = hr[k], wv = wr[k];
            a = fmaf(wv.x, h.x, a); a = fmaf(wv.y, h.y, a);
            a = fmaf(wv.z, h.z, a); a = fmaf(wv.w, h.w, a);
        }
        uu[i * 64 + t] = a;
    }
}

// ---------------------------------------------------------------------------
// Both affinities in one launch (grid 512): blocks <256 -> aff1, else final.
// ---------------------------------------------------------------------------
__global__ __launch_bounds__(256) void edge_kernel(
    const float* __restrict__ uu1, const float* __restrict__ uu2,
    const float* __restrict__ b1, const float* __restrict__ w2,
    const float* __restrict__ b2, float* __restrict__ out)
{
    __shared__ float sui[64], sw2[64], sb1[64];
    const int t = threadIdx.x, blk = blockIdx.x;
    const float* u = (blk < NDET) ? uu1 : uu2;
    float* o = (blk < NDET) ? out : out + NDET * NTRK;
    const int i = blk & (NDET - 1);
    if (t < 64) { sui[t] = u[i * 64 + t]; sw2[t] = w2[t]; sb1[t] = b1[t]; }
    __syncthreads();
    const float4* ur = (const float4*)(u + t * 64);
    float a = b2[0];
#pragma unroll
    for (int k = 0; k < 16; ++k) {
        const float4 uv = ur[k];
        const int k4 = k * 4;
        a = fmaf(sw2[k4 + 0], fmaxf(uv.x - sui[k4 + 0] + sb1[k4 + 0], 0.f), a);
        a = fmaf(sw2[k4 + 1], fmaxf(uv.y - sui[k4 + 1] + sb1[k4 + 1], 0.f), a);
        a = fmaf(sw2[k4 + 2], fmaxf(uv.z - sui[k4 + 2] + sb1[k4 + 2], 0.f), a);
        a = fmaf(sw2[k4 + 3], fmaxf(uv.w - sui[k4 + 3] + sb1[k4 + 3], 0.f), a);
    }
    o[i * 256 + t] = 1.f / (1.f + __expf(-a));
}

// ---------------------------------------------------------------------------
extern "C" void kernel_launch(void* const* d_in, const int* in_sizes, int n_in,
                              void* d_out, int out_size, void* d_ws, size_t ws_size,
                              hipStream_t stream)
{
    const float* det_pts     = (const float*)d_in[0];
    const float* det_boxes   = (const float*)d_in[1];
    const float* track_pts   = (const float*)d_in[2];
    const float* track_boxes = (const float*)d_in[3];
    const int*   adj         = (const int*)d_in[4];
    const float* pn_w1 = (const float*)d_in[5],  *pn_b1 = (const float*)d_in[6];
    const float* pn_w2 = (const float*)d_in[7],  *pn_b2 = (const float*)d_in[8];
    const float* pn_w3 = (const float*)d_in[9],  *pn_b3 = (const float*)d_in[10];
    const float* dm_w1 = (const float*)d_in[11], *dm_b1 = (const float*)d_in[12];
    const float* dm_w2 = (const float*)d_in[13], *dm_b2 = (const float*)d_in[14];
    const float* l0_wih = (const float*)d_in[15], *l0_whh = (const float*)d_in[16];
    const float* l0_bih = (const float*)d_in[17], *l0_bhh = (const float*)d_in[18];
    const float* l1_wih = (const float*)d_in[19], *l1_whh = (const float*)d_in[20];
    const float* l1_bih = (const float*)d_in[21], *l1_bhh = (const float*)d_in[22];
    const float* gc_wt = (const float*)d_in[23], *gc_bt = (const float*)d_in[24];
    const float* gc_wp = (const float*)d_in[25], *gc_bp = (const float*)d_in[26];
    const float* er_w1 = (const float*)d_in[27], *er_b1 = (const float*)d_in[28];
    const float* er_w2 = (const float*)d_in[29], *er_b2 = (const float*)d_in[30];
    float* out = (float*)d_out;

    float* hA  = (float*)d_ws;           // [512][128]
    float* Th  = hA  + NV * 128;         // [512][128]
    float* Ph  = Th  + NV * 128;         // [512][128]
    float* Th2 = Ph  + NV * 128;         // [512][128]
    float* Ph2 = Th2 + NV * 128;         // [512][128]
    float* uu1 = Ph2 + NV * 128;         // [256][64]
    float* uu2 = uu1 + NDET * 64;        // [256][64]

    pointnet_kernel<<<NV, 256, 0, stream>>>(det_pts, track_pts,
        pn_w1, pn_b1, pn_w2, pn_b2, pn_w3, pn_b3,
        det_boxes, dm_w1, dm_b1, dm_w2, dm_b2, hA);
    lstm_kernel<<<NTRK, 256, 0, stream>>>(track_boxes,
        l0_wih, l0_whh, l0_bih, l0_bhh, l1_wih, l1_whh, l1_bih, l1_bhh, hA);

    econv_gemm_kernel<<<NV, 128, 0, stream>>>(hA, gc_wt, gc_wp, gc_bp, Th, Ph);

    const size_t WSZ = 128 * 128;
    econv_fused_kernel<<<NV, 128, 0, stream>>>(adj, Th, Ph, gc_bt,
        gc_wt + WSZ, gc_wp + WSZ, gc_bp + 128, er_w1, uu1, Th2, Ph2);
    econv_fused_kernel<<<NV, 128, 0, stream>>>(adj, Th2, Ph2, gc_bt + 128,
        gc_wt + 2 * WSZ, gc_wp + 2 * WSZ, gc_bp + 256, nullptr, nullptr, Th, Ph);
    econv_fused_kernel<<<NV, 128, 0, stream>>>(adj, Th, Ph, gc_bt + 256,
        gc_wt + 3 * WSZ, gc_wp + 3 * WSZ, gc_bp + 384, nullptr, nullptr, Th2, Ph2);
    econv_fused_kernel<<<NV, 128, 0, stream>>>(adj, Th2, Ph2, gc_bt + 384,
        nullptr, nullptr, nullptr, er_w1, uu2, nullptr, nullptr);

    edge_kernel<<<NV, 256, 0, stream>>>(uu1, uu2, er_b1, er_w2, er_b2, out);
}

// Round 13
// 237.802 us; speedup vs baseline: 2.1804x; 1.0254x over previous
//
#include <hip/hip_runtime.h>
#include <math.h>

#define NDET 256
#define NTRK 256
#define NV   512
#define PPTS 512

typedef short bf16x8 __attribute__((ext_vector_type(8)));
typedef float f32x4  __attribute__((ext_vector_type(4)));

__device__ __forceinline__ float sigf(float x) { return 1.f / (1.f + __expf(-x)); }
__device__ __forceinline__ float ftanh(float x) {
    const float xc = fmaxf(fminf(x, 15.f), -15.f);   // avoid inf/inf
    const float e = __expf(2.f * xc);
    return (e - 1.f) / (e + 1.f);
}

__device__ __forceinline__ short f2bf(float f) {
    unsigned u = __float_as_uint(f);
    u += 0x7fffu + ((u >> 16) & 1u);          // RNE
    return (short)(u >> 16);
}
__device__ __forceinline__ unsigned pack2bf(float lo, float hi) {
    return (unsigned)(unsigned short)f2bf(lo) | ((unsigned)(unsigned short)f2bf(hi) << 16);
}
__device__ __forceinline__ bf16x8 load_frag_bf16(const float* __restrict__ src) {
    const float4 a = *(const float4*)src;
    const float4 b = *(const float4*)(src + 4);
    bf16x8 r;
    r[0] = f2bf(a.x); r[1] = f2bf(a.y); r[2] = f2bf(a.z); r[3] = f2bf(a.w);
    r[4] = f2bf(b.x); r[5] = f2bf(b.y); r[6] = f2bf(b.z); r[7] = f2bf(b.w);
    return r;
}

// ---------------------------------------------------------------------------
// PointNet, 2-way point-split: grid 1024, block (bb, s) handles points
// s*256..s*256+255 of object bb (4 chunks of 64). Partial 64-dim maxes go to
// pp[1024][64]; econv_gemm composes max(pp_a, pp_b) + b3 (exactly
// associative -> bit-identical). Fixes grid-limited occupancy (was 512
// blocks = 2/CU regardless of resources — R9/R12 analysis).
// det-motion tail runs on s==0 det blocks.
// ---------------------------------------------------------------------------
__global__ __launch_bounds__(256) void pointnet_kernel(
    const float* __restrict__ det_pts, const float* __restrict__ track_pts,
    const float* __restrict__ w1, const float* __restrict__ b1,
    const float* __restrict__ w2, const float* __restrict__ b2,
    const float* __restrict__ w3,
    const float* __restrict__ det_boxes,
    const float* __restrict__ dw1, const float* __restrict__ db1,
    const float* __restrict__ dw2, const float* __restrict__ db2,
    float* __restrict__ pp, float* __restrict__ hout)
{
    __shared__ __align__(16) short sH1[64][72];
    __shared__ __align__(16) short sH2[64][136];
    __shared__ __align__(16) float sX[320];
    __shared__ float sW1f[64][6];
    __shared__ float sB1[64];
    __shared__ float sbox[9];
    __shared__ float sh32[32];

    const int t  = threadIdx.x;
    const int bb = blockIdx.x >> 1;     // object
    const int s  = blockIdx.x & 1;      // point-half
    const int w  = t >> 6;
    const int ln = t & 15;
    const int kq = (t >> 4) & 3;
    const float* x = ((bb < NDET) ? (det_pts + (size_t)bb * PPTS * 5)
                                  : (track_pts + (size_t)(bb - NDET) * PPTS * 5))
                     + (size_t)s * 1280;          // 256 points x 5

    for (int i = t; i < 320; i += 256) sW1f[i / 5][i % 5] = w1[i];
    if (t < 64) sB1[t] = b1[t];

    bf16x8 bf2[2][2];
#pragma unroll
    for (int nt = 0; nt < 2; ++nt)
#pragma unroll
        for (int Kt = 0; Kt < 2; ++Kt)
            bf2[nt][Kt] = load_frag_bf16(w2 + (size_t)(32 * w + 16 * nt + ln) * 64 + kq * 8 + 32 * Kt);
    bf16x8 bf3[4];
#pragma unroll
    for (int Kt = 0; Kt < 4; ++Kt)
        bf3[Kt] = load_frag_bf16(w3 + (size_t)(16 * w + ln) * 128 + kq * 8 + 32 * Kt);
    float bn[2];
#pragma unroll
    for (int nt = 0; nt < 2; ++nt) bn[nt] = b2[32 * w + 16 * nt + ln];
    __syncthreads();

    float runmax[4] = {-1e30f, -1e30f, -1e30f, -1e30f};

    const int pt = t & 63;
    for (int c = 0; c < 4; ++c) {
        for (int i = t; i < 320; i += 256) sX[i] = x[c * 320 + i];
        __syncthreads();
        {
            float xv[5];
#pragma unroll
            for (int k = 0; k < 5; ++k) xv[k] = sX[pt * 5 + k];
#pragma unroll
            for (int jj = 0; jj < 8; ++jj) {
                const int d0 = w * 16 + 2 * jj;
                float a0 = sB1[d0], a1 = sB1[d0 + 1];
#pragma unroll
                for (int k = 0; k < 5; ++k) {
                    a0 = fmaf(xv[k], sW1f[d0][k], a0);
                    a1 = fmaf(xv[k], sW1f[d0 + 1][k], a1);
                }
                *(unsigned*)&sH1[pt][d0] = pack2bf(fmaxf(a0, 0.f), fmaxf(a1, 0.f));
            }
        }
        __syncthreads();
        {
            bf16x8 af[4][2];
#pragma unroll
            for (int Mt = 0; Mt < 4; ++Mt)
#pragma unroll
                for (int Kt = 0; Kt < 2; ++Kt)
                    af[Mt][Kt] = *(const bf16x8*)&sH1[16 * Mt + ln][kq * 8 + 32 * Kt];
#pragma unroll
            for (int Mt = 0; Mt < 4; ++Mt) {
#pragma unroll
                for (int nt = 0; nt < 2; ++nt) {
                    f32x4 cacc = {0.f, 0.f, 0.f, 0.f};
                    cacc = __builtin_amdgcn_mfma_f32_16x16x32_bf16(af[Mt][0], bf2[nt][0], cacc, 0, 0, 0);
                    cacc = __builtin_amdgcn_mfma_f32_16x16x32_bf16(af[Mt][1], bf2[nt][1], cacc, 0, 0, 0);
                    const int col = 32 * w + 16 * nt + ln;
#pragma unroll
                    for (int r = 0; r < 4; ++r)
                        sH2[16 * Mt + kq * 4 + r][col] = f2bf(fmaxf(cacc[r] + bn[nt], 0.f));
                }
            }
        }
        __syncthreads();
        {
#pragma unroll
            for (int Mt = 0; Mt < 4; ++Mt) {
                f32x4 cacc = {0.f, 0.f, 0.f, 0.f};
#pragma unroll
                for (int Kt = 0; Kt < 4; ++Kt) {
                    const bf16x8 a = *(const bf16x8*)&sH2[16 * Mt + ln][kq * 8 + 32 * Kt];
                    cacc = __builtin_amdgcn_mfma_f32_16x16x32_bf16(a, bf3[Kt], cacc, 0, 0, 0);
                }
#pragma unroll
                for (int r = 0; r < 4; ++r) runmax[r] = fmaxf(runmax[r], cacc[r]);
            }
        }
        __syncthreads();
    }

    float rm = fmaxf(fmaxf(runmax[0], runmax[1]), fmaxf(runmax[2], runmax[3]));
    rm = fmaxf(rm, __shfl_xor(rm, 16));
    rm = fmaxf(rm, __shfl_xor(rm, 32));
    if ((t & 63) < 16) {
        const int n = 16 * w + ln;
        pp[(size_t)blockIdx.x * 64 + n] = rm;     // partial max, no b3 yet
    }

    if (bb < NDET && s == 0) {
        if (t < 9) sbox[t] = det_boxes[bb * 9 + t];
        __syncthreads();
        if (t < 32) {
            float a = db1[t];
#pragma unroll
            for (int k = 0; k < 9; ++k) a = fmaf(dw1[t * 9 + k], sbox[k], a);
            sh32[t] = fmaxf(a, 0.f);
        }
        __syncthreads();
        if (t < 64) {
            float a = db2[t];
#pragma unroll
            for (int k = 0; k < 32; ++k) a = fmaf(dw2[t * 32 + k], sh32[k], a);
            hout[(size_t)bb * 128 + 64 + t] = a;
        }
    }
}

// ---------------------------------------------------------------------------
// Fused 2-layer LSTM, row-parallel (VGPR 256, no spill). Fast transcendentals.
// ---------------------------------------------------------------------------
__global__ __launch_bounds__(256, 1) void lstm_kernel(
    const float* __restrict__ track_boxes,
    const float* __restrict__ wih0, const float* __restrict__ whh0,
    const float* __restrict__ bih0, const float* __restrict__ bhh0,
    const float* __restrict__ wih1, const float* __restrict__ whh1,
    const float* __restrict__ bih1, const float* __restrict__ bhh1,
    float* __restrict__ hout)
{
    __shared__ float sx[90];
    __shared__ float sg[256];
    __shared__ __align__(16) float sh0[64];
    __shared__ __align__(16) float sh1[64];

    const int t = threadIdx.x;
    const int m = blockIdx.x;
    const int u = t & 63;

    if (t < 90) sx[t] = track_boxes[m * 90 + t];
    if (t < 64) { sh0[t] = 0.f; sh1[t] = 0.f; }

    float w0[9];
#pragma unroll
    for (int k = 0; k < 9; ++k) w0[k] = wih0[t * 9 + k];
    float4 wr0[16], wi1[16], wr1[16];
    {
        const float4* p0 = (const float4*)(whh0 + t * 64);
        const float4* p1 = (const float4*)(wih1 + t * 64);
        const float4* p2 = (const float4*)(whh1 + t * 64);
#pragma unroll
        for (int k = 0; k < 16; ++k) { wr0[k] = p0[k]; wi1[k] = p1[k]; wr1[k] = p2[k]; }
    }
    const float bias0 = bih0[t] + bhh0[t];
    const float bias1 = bih1[t] + bhh1[t];

    float c0 = 0.f, c1 = 0.f, h1reg = 0.f;
    __syncthreads();

    for (int s = 0; s < 10; ++s) {
        {
            float acc0 = bias0, acc1 = 0.f, acc2 = 0.f, acc3 = 0.f;
#pragma unroll
            for (int k = 0; k < 9; ++k) acc0 = fmaf(w0[k], sx[s * 9 + k], acc0);
            const float4* hv = (const float4*)sh0;
#pragma unroll
            for (int k = 0; k < 16; k += 4) {
                float4 hA = hv[k], hB = hv[k + 1], hC = hv[k + 2], hD = hv[k + 3];
                acc0 = fmaf(wr0[k].x, hA.x, acc0); acc0 = fmaf(wr0[k].y, hA.y, acc0);
                acc0 = fmaf(wr0[k].z, hA.z, acc0); acc0 = fmaf(wr0[k].w, hA.w, acc0);
                acc1 = fmaf(wr0[k+1].x, hB.x, acc1); acc1 = fmaf(wr0[k+1].y, hB.y, acc1);
                acc1 = fmaf(wr0[k+1].z, hB.z, acc1); acc1 = fmaf(wr0[k+1].w, hB.w, acc1);
                acc2 = fmaf(wr0[k+2].x, hC.x, acc2); acc2 = fmaf(wr0[k+2].y, hC.y, acc2);
                acc2 = fmaf(wr0[k+2].z, hC.z, acc2); acc2 = fmaf(wr0[k+2].w, hC.w, acc2);
                acc3 = fmaf(wr0[k+3].x, hD.x, acc3); acc3 = fmaf(wr0[k+3].y, hD.y, acc3);
                acc3 = fmaf(wr0[k+3].z, hD.z, acc3); acc3 = fmaf(wr0[k+3].w, hD.w, acc3);
            }
            sg[t] = (acc0 + acc1) + (acc2 + acc3);
        }
        __syncthreads();
        if (t < 64) {
            const float gi = sg[u], gf = sg[64 + u], gg = sg[128 + u], go = sg[192 + u];
            c0 = sigf(gf) * c0 + sigf(gi) * ftanh(gg);
            sh0[u] = sigf(go) * ftanh(c0);
        }
        __syncthreads();
        {
            float acc0 = bias1, acc1 = 0.f, acc2 = 0.f, acc3 = 0.f;
            const float4* xv = (const float4*)sh0;
            const float4* hv = (const float4*)sh1;
#pragma unroll
            for (int k = 0; k < 16; k += 4) {
                float4 xA = xv[k], xB = xv[k + 1], xC = xv[k + 2], xD = xv[k + 3];
                acc0 = fmaf(wi1[k].x, xA.x, acc0); acc0 = fmaf(wi1[k].y, xA.y, acc0);
                acc0 = fmaf(wi1[k].z, xA.z, acc0); acc0 = fmaf(wi1[k].w, xA.w, acc0);
                acc1 = fmaf(wi1[k+1].x, xB.x, acc1); acc1 = fmaf(wi1[k+1].y, xB.y, acc1);
                acc1 = fmaf(wi1[k+1].z, xB.z, acc1); acc1 = fmaf(wi1[k+1].w, xB.w, acc1);
                acc2 = fmaf(wi1[k+2].x, xC.x, acc2); acc2 = fmaf(wi1[k+2].y, xC.y, acc2);
                acc2 = fmaf(wi1[k+2].z, xC.z, acc2); acc2 = fmaf(wi1[k+2].w, xC.w, acc2);
                acc3 = fmaf(wi1[k+3].x, xD.x, acc3); acc3 = fmaf(wi1[k+3].y, xD.y, acc3);
                acc3 = fmaf(wi1[k+3].z, xD.z, acc3); acc3 = fmaf(wi1[k+3].w, xD.w, acc3);
            }
#pragma unroll
            for (int k = 0; k < 16; k += 4) {
                float4 hA = hv[k], hB = hv[k + 1], hC = hv[k + 2], hD = hv[k + 3];
                acc0 = fmaf(wr1[k].x, hA.x, acc0); acc0 = fmaf(wr1[k].y, hA.y, acc0);
                acc0 = fmaf(wr1[k].z, hA.z, acc0); acc0 = fmaf(wr1[k].w, hA.w, acc0);
                acc1 = fmaf(wr1[k+1].x, hB.x, acc1); acc1 = fmaf(wr1[k+1].y, hB.y, acc1);
                acc1 = fmaf(wr1[k+1].z, hB.z, acc1); acc1 = fmaf(wr1[k+1].w, hB.w, acc1);
                acc2 = fmaf(wr1[k+2].x, hC.x, acc2); acc2 = fmaf(wr1[k+2].y, hC.y, acc2);
                acc2 = fmaf(wr1[k+2].z, hC.z, acc2); acc2 = fmaf(wr1[k+2].w, hC.w, acc2);
                acc3 = fmaf(wr1[k+3].x, hD.x, acc3); acc3 = fmaf(wr1[k+3].y, hD.y, acc3);
                acc3 = fmaf(wr1[k+3].z, hD.z, acc3); acc3 = fmaf(wr1[k+3].w, hD.w, acc3);
            }
            sg[t] = (acc0 + acc1) + (acc2 + acc3);
        }
        __syncthreads();
        if (t < 64) {
            const float gi = sg[u], gf = sg[64 + u], gg = sg[128 + u], go = sg[192 + u];
            c1 = sigf(gf) * c1 + sigf(gi) * ftanh(gg);
            h1reg = sigf(go) * ftanh(c1);
            sh1[u] = h1reg;
        }
        __syncthreads();
    }

    if (t < 64) hout[(size_t)(NDET + m) * 128 + 64 + u] = h1reg;
}

// ---------------------------------------------------------------------------
// EdgeConv layer-0 GEMMs: one block per vertex. Composes h row: cols 0-63
// from the two pointnet partial maxes (+b3), cols 64-127 from hA.
// ---------------------------------------------------------------------------
__global__ __launch_bounds__(128) void econv_gemm_kernel(
    const float* __restrict__ pp, const float* __restrict__ b3,
    const float* __restrict__ hin, const float* __restrict__ wt,
    const float* __restrict__ wp, const float* __restrict__ bp,
    float* __restrict__ Th, float* __restrict__ Ph)
{
    __shared__ __align__(16) float srow[128];
    const int t = threadIdx.x, v = blockIdx.x;
    srow[t] = (t < 64)
        ? fmaxf(pp[(size_t)v * 128 + t], pp[(size_t)v * 128 + 64 + t]) + b3[t]
        : hin[(size_t)v * 128 + t];
    __syncthreads();
    const float4* hr = (const float4*)srow;
    const float4* wtr = (const float4*)(wt + t * 128);
    const float4* wpr = (const float4*)(wp + t * 128);
    float aT = 0.f, aP = bp[t];
#pragma unroll 8
    for (int k = 0; k < 32; ++k) {
        const float4 h = hr[k];
        const float4 a = wtr[k];
        aT = fmaf(a.x, h.x, aT); aT = fmaf(a.y, h.y, aT);
        aT = fmaf(a.z, h.z, aT); aT = fmaf(a.w, h.w, aT);
        const float4 b = wpr[k];
        aP = fmaf(b.x, h.x, aP); aP = fmaf(b.y, h.y, aP);
        aP = fmaf(b.z, h.z, aP); aP = fmaf(b.w, h.w, aP);
    }
    Th[v * 128 + t] = aT;
    Ph[v * 128 + t] = aP;
}

// ---------------------------------------------------------------------------
// Fused EdgeConv, 256 threads: j-loop split 8-way (64 j/thread), then
// masked-max combine + relu in LDS; next-layer GEMM splits Th (t<128) and
// Ph (t>=128) across thread halves — per-dot k-order unchanged, and max is
// associative -> bit-identical to the 128-thread version.
// ---------------------------------------------------------------------------
__global__ __launch_bounds__(256) void econv_fused_kernel(
    const int* __restrict__ adj, const float* __restrict__ Th,
    const float* __restrict__ Ph, const float* __restrict__ bt,
    const float* __restrict__ wtn, const float* __restrict__ wpn,
    const float* __restrict__ bpn,
    const float* __restrict__ erw1, float* __restrict__ uu,
    float* __restrict__ Thn, float* __restrict__ Phn)
{
    __shared__ float sneg[NV];                       // 0 / -3e38 mask bias
    __shared__ __align__(16) float4 sred[8][32];     // per-group partial max
    __shared__ __align__(16) float sh[128];          // h_i row

    const int t = threadIdx.x, i = blockIdx.x;
    const int l32 = t & 31, grp = t >> 5;            // grp 0..7

    for (int j = t; j < NV; j += 256)
        sneg[j] = ((adj[j * NV + i] != 0) || (j == i)) ? 0.f : -3e38f;

    float thi = 0.f, phi = 0.f, btv = 0.f;
    if (t < 128) {
        thi = Th[i * 128 + t];
        phi = Ph[i * 128 + t];
        btv = bt[t];
    }
    __syncthreads();

    float4 mx = {-3e38f, -3e38f, -3e38f, -3e38f};
    const float* __restrict__ thp = Th + 4 * l32;
#pragma unroll 4
    for (int jb = 0; jb < NV; jb += 32) {
        float4 v[4];
#pragma unroll
        for (int jj = 0; jj < 4; ++jj)
            v[jj] = *(const float4*)&thp[(size_t)(jb + 4 * grp + jj) * 128];
#pragma unroll
        for (int jj = 0; jj < 4; ++jj) {
            const float s = sneg[jb + 4 * grp + jj];
            mx.x = fmaxf(mx.x, v[jj].x + s);
            mx.y = fmaxf(mx.y, v[jj].y + s);
            mx.z = fmaxf(mx.z, v[jj].z + s);
            mx.w = fmaxf(mx.w, v[jj].w + s);
        }
    }
    sred[grp][l32] = mx;
    __syncthreads();

    if (t < 128) {
        const float* rf = (const float*)sred;
        float m = rf[t];
#pragma unroll
        for (int g = 1; g < 8; ++g) m = fmaxf(m, rf[g * 128 + t]);
        sh[t] = fmaxf(m - thi + btv + phi, 0.f);
    }
    __syncthreads();

    const float4* hr = (const float4*)sh;
    if (wtn) {
        const int d = t & 127;
        const float* wsrc = (t < 128) ? wtn : wpn;
        const float4* wr = (const float4*)(wsrc + (size_t)d * 128);
        float acc = (t < 128) ? 0.f : bpn[d];
#pragma unroll 8
        for (int k = 0; k < 32; ++k) {
            const float4 h = hr[k], wv = wr[k];
            acc = fmaf(wv.x, h.x, acc); acc = fmaf(wv.y, h.y, acc);
            acc = fmaf(wv.z, h.z, acc); acc = fmaf(wv.w, h.w, acc);
        }
        if (t < 128) Thn[i * 128 + d] = acc;
        else         Phn[i * 128 + d] = acc;
    }
    if (erw1 && i < NDET && t < 64) {
        const float4* wr = (const float4*)(erw1 + (size_t)t * 128);
        float a = 0.f;
#pragma unroll 8
        for (int k = 0; k < 32; ++k) {
            const float4 h = hr[k], wv = wr[k];
            a = fmaf(wv.x, h.x, a); a = fmaf(wv.y, h.y, a);
            a = fmaf(wv.z, h.z, a); a = fmaf(wv.w, h.w, a);
        }
        uu[i * 64 + t] = a;
    }
}

// ---------------------------------------------------------------------------
// Both affinities in one launch (grid 512): blocks <256 -> aff1, else final.
// ---------------------------------------------------------------------------
__global__ __launch_bounds__(256) void edge_kernel(
    const float* __restrict__ uu1, const float* __restrict__ uu2,
    const float* __restrict__ b1, const float* __restrict__ w2,
    const float* __restrict__ b2, float* __restrict__ out)
{
    __shared__ float sui[64], sw2[64], sb1[64];
    const int t = threadIdx.x, blk = blockIdx.x;
    const float* u = (blk < NDET) ? uu1 : uu2;
    float* o = (blk < NDET) ? out : out + NDET * NTRK;
    const int i = blk & (NDET - 1);
    if (t < 64) { sui[t] = u[i * 64 + t]; sw2[t] = w2[t]; sb1[t] = b1[t]; }
    __syncthreads();
    const float4* ur = (const float4*)(u + t * 64);
    float a = b2[0];
#pragma unroll
    for (int k = 0; k < 16; ++k) {
        const float4 uv = ur[k];
        const int k4 = k * 4;
        a = fmaf(sw2[k4 + 0], fmaxf(uv.x - sui[k4 + 0] + sb1[k4 + 0], 0.f), a);
        a = fmaf(sw2[k4 + 1], fmaxf(uv.y - sui[k4 + 1] + sb1[k4 + 1], 0.f), a);
        a = fmaf(sw2[k4 + 2], fmaxf(uv.z - sui[k4 + 2] + sb1[k4 + 2], 0.f), a);
        a = fmaf(sw2[k4 + 3], fmaxf(uv.w - sui[k4 + 3] + sb1[k4 + 3], 0.f), a);
    }
    o[i * 256 + t] = 1.f / (1.f + __expf(-a));
}

// ---------------------------------------------------------------------------
extern "C" void kernel_launch(void* const* d_in, const int* in_sizes, int n_in,
                              void* d_out, int out_size, void* d_ws, size_t ws_size,
                              hipStream_t stream)
{
    const float* det_pts     = (const float*)d_in[0];
    const float* det_boxes   = (const float*)d_in[1];
    const float* track_pts   = (const float*)d_in[2];
    const float* track_boxes = (const float*)d_in[3];
    const int*   adj         = (const int*)d_in[4];
    const float* pn_w1 = (const float*)d_in[5],  *pn_b1 = (const float*)d_in[6];
    const float* pn_w2 = (const float*)d_in[7],  *pn_b2 = (const float*)d_in[8];
    const float* pn_w3 = (const float*)d_in[9],  *pn_b3 = (const float*)d_in[10];
    const float* dm_w1 = (const float*)d_in[11], *dm_b1 = (const float*)d_in[12];
    const float* dm_w2 = (const float*)d_in[13], *dm_b2 = (const float*)d_in[14];
    const float* l0_wih = (const float*)d_in[15], *l0_whh = (const float*)d_in[16];
    const float* l0_bih = (const float*)d_in[17], *l0_bhh = (const float*)d_in[18];
    const float* l1_wih = (const float*)d_in[19], *l1_whh = (const float*)d_in[20];
    const float* l1_bih = (const float*)d_in[21], *l1_bhh = (const float*)d_in[22];
    const float* gc_wt = (const float*)d_in[23], *gc_bt = (const float*)d_in[24];
    const float* gc_wp = (const float*)d_in[25], *gc_bp = (const float*)d_in[26];
    const float* er_w1 = (const float*)d_in[27], *er_b1 = (const float*)d_in[28];
    const float* er_w2 = (const float*)d_in[29], *er_b2 = (const float*)d_in[30];
    float* out = (float*)d_out;

    float* hA  = (float*)d_ws;           // [512][128]
    float* Th  = hA  + NV * 128;         // [512][128]
    float* Ph  = Th  + NV * 128;         // [512][128]
    float* Th2 = Ph  + NV * 128;         // [512][128]
    float* Ph2 = Th2 + NV * 128;         // [512][128]
    float* uu1 = Ph2 + NV * 128;         // [256][64]
    float* uu2 = uu1 + NDET * 64;        // [256][64]
    float* pp  = uu2 + NDET * 64;        // [1024][64] pointnet partial maxes

    pointnet_kernel<<<2 * NV, 256, 0, stream>>>(det_pts, track_pts,
        pn_w1, pn_b1, pn_w2, pn_b2, pn_w3,
        det_boxes, dm_w1, dm_b1, dm_w2, dm_b2, pp, hA);
    lstm_kernel<<<NTRK, 256, 0, stream>>>(track_boxes,
        l0_wih, l0_whh, l0_bih, l0_bhh, l1_wih, l1_whh, l1_bih, l1_bhh, hA);

    econv_gemm_kernel<<<NV, 128, 0, stream>>>(pp, pn_b3, hA,
        gc_wt, gc_wp, gc_bp, Th, Ph);

    const size_t WSZ = 128 * 128;
    econv_fused_kernel<<<NV, 256, 0, stream>>>(adj, Th, Ph, gc_bt,
        gc_wt + WSZ, gc_wp + WSZ, gc_bp + 128, er_w1, uu1, Th2, Ph2);
    econv_fused_kernel<<<NV, 256, 0, stream>>>(adj, Th2, Ph2, gc_bt + 128,
        gc_wt + 2 * WSZ, gc_wp + 2 * WSZ, gc_bp + 256, nullptr, nullptr, Th, Ph);
    econv_fused_kernel<<<NV, 256, 0, stream>>>(adj, Th, Ph, gc_bt + 256,
        gc_wt + 3 * WSZ, gc_wp + 3 * WSZ, gc_bp + 384, nullptr, nullptr, Th2, Ph2);
    econv_fused_kernel<<<NV, 256, 0, stream>>>(adj, Th2, Ph2, gc_bt + 384,
        nullptr, nullptr, nullptr, er_w1, uu2, nullptr, nullptr);

    edge_kernel<<<NV, 256, 0, stream>>>(uu1, uu2, er_b1, er_w2, er_b2, out);
}